// Round 4
// baseline (263.827 us; speedup 1.0000x reference)
//
#include <hip/hip_runtime.h>
#include <cstdint>

constexpr int Sd = 1024;
constexpr int Td = 48;
constexpr int NTAG = 45;    // normal tags 0..44
constexpr int START_ = 45;
constexpr int STOP_ = 46;

typedef float v2f __attribute__((ext_vector_type(2)));
typedef float v4f __attribute__((ext_vector_type(4)));

// R2's proven per-chain step (own write -> fence -> 12 broadcast b128 reads),
// parameterized by the wave's matrix M2 (E rows for fwd wave, E^T rows for bwd).
//   tot = M . r            (r = broadcast of previous vector)
//   k   = exponent(r[0])   (exact power-of-2 late renorm, wave-uniform)
//   v   = tot * exp(PF) * 2^-k     (if ACT; frozen otherwise)
//   uf  = tot * 2^-k               (bwd meeting-point capture, exact)
#define CRF_STEP(X, PF, ACT) do {                                              \
    v2f a0_={0.f,0.f},a1_={0.f,0.f},a2_={0.f,0.f},a3_={0.f,0.f};               \
    _Pragma("unroll")                                                          \
    for (int q_=0;q_<12;q_+=2){                                                \
        v2f lo0_={r##X[q_].x,r##X[q_].y},   hi0_={r##X[q_].z,r##X[q_].w};      \
        v2f lo1_={r##X[q_+1].x,r##X[q_+1].y}, hi1_={r##X[q_+1].z,r##X[q_+1].w};\
        a0_=__builtin_elementwise_fma(M2[2*q_],  lo0_,a0_);                    \
        a1_=__builtin_elementwise_fma(M2[2*q_+1],hi0_,a1_);                    \
        a2_=__builtin_elementwise_fma(M2[2*q_+2],lo1_,a2_);                    \
        a3_=__builtin_elementwise_fma(M2[2*q_+3],hi1_,a3_);                    \
    }                                                                          \
    v2f s_=(a0_+a1_)+(a2_+a3_);                                                \
    float tot_=s_.x+s_.y;                                                      \
    int k_=(int)((__float_as_uint(r##X[0].x)>>23)&0xFFu)-127;                  \
    float sc_=__uint_as_float((uint32_t)(127-k_)<<23);                         \
    float vn_=tot_*(__expf(PF)*sc_);                                           \
    v##X=(ACT)?vn_:v##X;                                                       \
    L##X+=(ACT)?k_:0;                                                          \
    uf##X=(ACT)?tot_*sc_:uf##X;                                                \
    if (vlane) vb##X[lane]=v##X;                                               \
    asm volatile("" ::: "memory");                                             \
    _Pragma("unroll")                                                          \
    for (int q_=0;q_<12;++q_) r##X[q_]=((const v4f*)vb##X)[q_];                \
} while (0)

__launch_bounds__(128, 1)
__global__ void crf_fb2(const float* __restrict__ feats,
                        const float* __restrict__ masks,
                        const int* __restrict__ tags,
                        const float* __restrict__ trans,
                        float* __restrict__ out)
{
    __shared__ float tl[Td * Td];
    __shared__ __align__(16) float vls[4][Td];   // 0:fwdA 1:fwdB 2:bwdA 3:bwdB
    __shared__ int shL[4];                       // LFA, LFB, LBA, LBB

    const int tid  = threadIdx.x;
    const int lane = tid & 63;
    const int wid  = tid >> 6;
    const bool fwd = (wid == 0);
    const int bA = blockIdx.x * 2;
    const int bB = bA + 1;

    for (int i = tid; i < Td * Td; i += 128) tl[i] = trans[i];
    __syncthreads();

    const size_t bSA = (size_t)bA * Sd;
    const size_t bSB = (size_t)bB * Sd;

    // ---- lengths (each wave computes both; cheap, cached) ----
    auto get_len = [&](size_t bS) {
        float c = 0.f;
        for (int t = lane; t < Sd; t += 64) c += masks[bS + t];
#pragma unroll
        for (int off = 32; off; off >>= 1) c += __shfl_xor(c, off);
        int l = (int)(c + 0.5f);
        return l < 1 ? 1 : l;
    };
    const int lenA = get_len(bSA);
    const int lenB = get_len(bSB);

    // ---- gold score: wave0 -> batch A, wave1 -> batch B ----
    const size_t bSg = fwd ? bSA : bSB;
    const int    leng = fwd ? lenA : lenB;
    float g = 0.f;
    for (int t = lane; t < leng; t += 64) {
        const int tag  = tags[bSg + t];
        const int prev = (t == 0) ? START_ : tags[bSg + t - 1];
        g += feats[(bSg + t) * Td + tag] + tl[tag * Td + prev];
    }
#pragma unroll
    for (int off = 32; off; off >>= 1) g += __shfl_xor(g, off);
    g += tl[STOP_ * Td + tags[bSg + leng - 1]];

    // ---- per-wave matrix: wave0 = E rows, wave1 = E^T rows ----
    const bool vlane = (lane < Td);
    v2f M2[24];
    if (fwd) {
        const bool ok = (lane < NTAG);           // rows 45..47 are exact sinks
#pragma unroll
        for (int q = 0; q < 24; ++q) {
            M2[q].x = ok ? __expf(tl[lane * Td + 2*q])     : 0.f;
            M2[q].y = ok ? __expf(tl[lane * Td + 2*q + 1]) : 0.f;
        }
    } else {
#pragma unroll
        for (int q = 0; q < 24; ++q) {
            M2[q].x = vlane ? __expf(tl[(2*q)   * Td + lane]) : 0.f;
            M2[q].y = vlane ? __expf(tl[(2*q+1) * Td + lane]) : 0.f;
        }
    }
    // fwd: M2[22].y = E[lane][START];  bwd: M2[23].x = E^T[lane][STOP] = wstop
    const int lidx = vlane ? lane : 0;
    const float* frowA = feats + bSA * Td;
    const float* frowB = feats + bSB * Td;

    // ---- meet-in-the-middle split ----
    const int FA = (lenA + 1) >> 1, NBA = lenA - FA;
    const int FB = (lenB + 1) >> 1, NBB = lenB - FB;
    const int actA = fwd ? (FA - 1) : NBA;
    const int actB = fwd ? (FB - 1) : NBB;
    const int TRIP = actA > actB ? actA : actB;

    // emission index consumed at superstep t (wave-uniform select)
    auto eA = [&](int t) { return fwd ? (((t+1) < FA) ? (t+1) : 0)
                                      : ((t < NBA) ? (lenA - 2 - t) : 0); };
    auto eB = [&](int t) { return fwd ? (((t+1) < FB) ? (t+1) : 0)
                                      : ((t < NBB) ? (lenB - 2 - t) : 0); };

    // ---- chain inits ----
    float vA = fwd ? __expf(frowA[lidx]) * M2[22].y
                   : M2[23].x * __expf(frowA[(size_t)(lenA - 1) * Td + lidx]);
    float vB = fwd ? __expf(frowB[lidx]) * M2[22].y
                   : M2[23].x * __expf(frowB[(size_t)(lenB - 1) * Td + lidx]);
    float ufA = M2[23].x, ufB = M2[23].x;        // bwd: = wstop when NB==0
    int LA = 0, LB = 0;

    float* vbA = &vls[wid * 2][0];
    float* vbB = &vls[wid * 2 + 1][0];
    if (vlane) { vbA[lane] = vA; vbB[lane] = vB; }
    asm volatile("" ::: "memory");
    v4f rA[12], rB[12];
#pragma unroll
    for (int q = 0; q < 12; ++q) {
        rA[q] = ((const v4f*)vbA)[q];
        rB[q] = ((const v4f*)vbB)[q];
    }

    // ---- emission prefetch, depth 4 per chain ----
    float pf0A = frowA[(size_t)eA(0) * Td + lidx];
    float pf1A = frowA[(size_t)eA(1) * Td + lidx];
    float pf2A = frowA[(size_t)eA(2) * Td + lidx];
    float pf3A = frowA[(size_t)eA(3) * Td + lidx];
    float pf0B = frowB[(size_t)eB(0) * Td + lidx];
    float pf1B = frowB[(size_t)eB(1) * Td + lidx];
    float pf2B = frowB[(size_t)eB(2) * Td + lidx];
    float pf3B = frowB[(size_t)eB(3) * Td + lidx];

    int k = 0;
    while (k + 4 <= TRIP) {
        {
            const bool aA = (k < actA), aB = (k < actB);
            CRF_STEP(A, pf0A, aA);
            CRF_STEP(B, pf0B, aB);
            const int tn = k + 4;
            pf0A = frowA[(size_t)eA(tn) * Td + lidx];
            pf0B = frowB[(size_t)eB(tn) * Td + lidx];
        }
        {
            const bool aA = (k + 1 < actA), aB = (k + 1 < actB);
            CRF_STEP(A, pf1A, aA);
            CRF_STEP(B, pf1B, aB);
            const int tn = k + 5;
            pf1A = frowA[(size_t)eA(tn) * Td + lidx];
            pf1B = frowB[(size_t)eB(tn) * Td + lidx];
        }
        {
            const bool aA = (k + 2 < actA), aB = (k + 2 < actB);
            CRF_STEP(A, pf2A, aA);
            CRF_STEP(B, pf2B, aB);
            const int tn = k + 6;
            pf2A = frowA[(size_t)eA(tn) * Td + lidx];
            pf2B = frowB[(size_t)eB(tn) * Td + lidx];
        }
        {
            const bool aA = (k + 3 < actA), aB = (k + 3 < actB);
            CRF_STEP(A, pf3A, aA);
            CRF_STEP(B, pf3B, aB);
            const int tn = k + 7;
            pf3A = frowA[(size_t)eA(tn) * Td + lidx];
            pf3B = frowB[(size_t)eB(tn) * Td + lidx];
        }
        k += 4;
    }
    if (k < TRIP) { const bool aA = k < actA, aB = k < actB; CRF_STEP(A, pf0A, aA); CRF_STEP(B, pf0B, aB); ++k; }
    if (k < TRIP) { const bool aA = k < actA, aB = k < actB; CRF_STEP(A, pf1A, aA); CRF_STEP(B, pf1B, aB); ++k; }
    if (k < TRIP) { const bool aA = k < actA, aB = k < actB; CRF_STEP(A, pf2A, aA); CRF_STEP(B, pf2B, aB); ++k; }

    // ---- publish meeting pieces ----
    if (!fwd && vlane) { vls[2][lane] = ufA; vls[3][lane] = ufB; }
    if (lane == 0) { shL[wid * 2] = LA; shL[wid * 2 + 1] = LB; }
    __syncthreads();

    // wave0 finishes batch A (vls[0].vls[2]); wave1 finishes batch B (vls[1].vls[3])
    const float* pv = fwd ? &vls[0][0] : &vls[1][0];
    const float* pu = fwd ? &vls[2][0] : &vls[3][0];
    float p = vlane ? pv[lane] * pu[lane] : 0.f;
#pragma unroll
    for (int off = 32; off; off >>= 1) p += __shfl_xor(p, off);

    if (lane == 0) {
        const int Lt = fwd ? (shL[0] + shL[2]) : (shL[1] + shL[3]);
        const float ln2 = 0.6931471805599453f;
        out[fwd ? bA : bB] = (float)Lt * ln2 + __logf(p) - g;
    }
}

extern "C" void kernel_launch(void* const* d_in, const int* in_sizes, int n_in,
                              void* d_out, int out_size, void* d_ws, size_t ws_size,
                              hipStream_t stream) {
    const float* feats = (const float*)d_in[0];
    const float* masks = (const float*)d_in[1];
    const int*   tags  = (const int*)d_in[2];
    const float* trans = (const float*)d_in[3];
    float* outp = (float*)d_out;

    const int Bn = in_sizes[1] / Sd;     // B = 512
    crf_fb2<<<dim3(Bn / 2), dim3(128), 0, stream>>>(feats, masks, tags, trans, outp);
}

// Round 5
// 253.705 us; speedup vs baseline: 1.0399x; 1.0399x over previous
//
#include <hip/hip_runtime.h>
#include <cstdint>

constexpr int Sd = 1024;
constexpr int Td = 48;
constexpr int NTAG = 45;    // normal tags 0..44
constexpr int START_ = 45;
constexpr int STOP_ = 46;

typedef float v2f __attribute__((ext_vector_type(2)));
typedef float v4f __attribute__((ext_vector_type(4)));

__device__ __forceinline__ int rfl_i(int x) { return __builtin_amdgcn_readfirstlane(x); }

// One chain step (R2's proven shape + producer-side scalar renorm):
//   tot = M . r            (r = broadcast of last written vector, 12 x b128)
//   vn  = tot * exp(PF) * sc   (sc = scalar 2^-k, computed last step)
//   freeze via scalar act count; then k,sc for NEXT step from readfirstlane(v)
#define STEP_ONE(X, PF, K_) do {                                               \
    v2f a0_={0.f,0.f},a1_={0.f,0.f},a2_={0.f,0.f},a3_={0.f,0.f};               \
    _Pragma("unroll")                                                          \
    for (int q_=0;q_<12;q_+=2){                                                \
        v2f lo0_={r##X[q_].x,r##X[q_].y},   hi0_={r##X[q_].z,r##X[q_].w};      \
        v2f lo1_={r##X[q_+1].x,r##X[q_+1].y}, hi1_={r##X[q_+1].z,r##X[q_+1].w};\
        a0_=__builtin_elementwise_fma(M2[2*q_],  lo0_,a0_);                    \
        a1_=__builtin_elementwise_fma(M2[2*q_+1],hi0_,a1_);                    \
        a2_=__builtin_elementwise_fma(M2[2*q_+2],lo1_,a2_);                    \
        a3_=__builtin_elementwise_fma(M2[2*q_+3],hi1_,a3_);                    \
    }                                                                          \
    v2f s_=(a0_+a1_)+(a2_+a3_);                                                \
    float tot_=s_.x+s_.y;                                                      \
    float vn_=tot_*(__expf(PF)*sc##X);                                         \
    const bool a_=((K_)<act##X);                                               \
    v##X = a_ ? vn_ : v##X;                                                    \
    uf##X = a_ ? tot_*sc##X : uf##X;                                           \
    L##X += a_ ? kx##X : 0;                                                    \
    { int kb_=rfl_i(__float_as_int(v##X));                                     \
      kx##X=((kb_>>23)&0xFF)-127;                                              \
      sc##X=__int_as_float((127-kx##X)<<23); }                                 \
    if (vlane) vls[CH_##X][lane]=v##X;                                         \
    asm volatile("" ::: "memory");                                             \
    _Pragma("unroll")                                                          \
    for (int q_=0;q_<12;++q_) r##X[q_]=((const v4f*)vls[CH_##X])[q_];          \
} while (0)

// scalar pointer advance for the emission prefetch stream
#define ADV(X) do {                                                            \
    const bool adv_ = isb ? (t##X > 0) : (t##X < hi##X);                       \
    p##X += adv_ ? sAdv : 0;                                                   \
    t##X += adv_ ? sInc : 0;                                                   \
} while (0)

constexpr int CH_A = 0;
constexpr int CH_B = 1;

__launch_bounds__(64)
__global__ void crf_chains(const float* __restrict__ feats,
                           const float* __restrict__ masks,
                           const int* __restrict__ tags,
                           const float* __restrict__ trans,
                           float* __restrict__ wsv,   // [48][Bn] fwd meeting vec
                           float* __restrict__ wsu,   // [48][Bn] bwd meeting vec
                           int* __restrict__ wsLF, int* __restrict__ wsLB,
                           float* __restrict__ wsg,   // [Bn] gold
                           int Bn)
{
    __shared__ float tl[Td * Td];
    __shared__ __align__(16) float vls[2][Td];

    const int lane = threadIdx.x;
    const int nPair = Bn >> 1;
    const bool isb = (blockIdx.x >= nPair);          // block-uniform direction
    const int pair = isb ? (blockIdx.x - nPair) : blockIdx.x;
    const int bA = pair * 2;
    const int bB = bA + 1;

    for (int i = lane; i < Td * Td; i += 64) tl[i] = trans[i];
    __syncthreads();

    const size_t bSA = (size_t)bA * Sd;
    const size_t bSB = (size_t)bB * Sd;

    // ---- lengths (scalar) ----
    auto get_len = [&](size_t bS) {
        float c = 0.f;
        for (int t = lane; t < Sd; t += 64) c += masks[bS + t];
#pragma unroll
        for (int off = 32; off; off >>= 1) c += __shfl_xor(c, off);
        int l = (int)(c + 0.5f);
        return rfl_i(l < 1 ? 1 : l);
    };
    const int lenA = get_len(bSA);
    const int lenB = get_len(bSB);

    // ---- gold scores (fwd blocks only) ----
    if (!isb) {
        auto get_gold = [&](size_t bS, int len) {
            float g = 0.f;
            for (int t = lane; t < len; t += 64) {
                const int tag  = tags[bS + t];
                const int prev = (t == 0) ? START_ : tags[bS + t - 1];
                g += feats[(bS + t) * Td + tag] + tl[tag * Td + prev];
            }
#pragma unroll
            for (int off = 32; off; off >>= 1) g += __shfl_xor(g, off);
            return g + tl[STOP_ * Td + tags[bS + len - 1]];
        };
        const float gA = get_gold(bSA, lenA);
        const float gB = get_gold(bSB, lenB);
        if (lane == 0) { wsg[bA] = gA; wsg[bB] = gB; }
    }

    // ---- per-direction matrix row (48 VGPRs) ----
    const bool vlane = (lane < Td);
    v2f M2[24];
    if (!isb) {                                      // fwd: E rows, sinks zeroed
        const bool ok = (lane < NTAG);
#pragma unroll
        for (int q = 0; q < 24; ++q) {
            M2[q].x = ok ? __expf(tl[lane * Td + 2*q])     : 0.f;
            M2[q].y = ok ? __expf(tl[lane * Td + 2*q + 1]) : 0.f;
        }
    } else {                                         // bwd: E^T rows
#pragma unroll
        for (int q = 0; q < 24; ++q) {
            M2[q].x = vlane ? __expf(tl[(2*q)   * Td + lane]) : 0.f;
            M2[q].y = vlane ? __expf(tl[(2*q+1) * Td + lane]) : 0.f;
        }
    }
    // fwd: M2[22].y = E[lane][START]; bwd: M2[23].x = E^T[lane][STOP] = wstop
    const int lidx = vlane ? lane : 0;
    const float* frowA = feats + bSA * Td;
    const float* frowB = feats + bSB * Td;

    // ---- split: fwd runs F-1 steps, bwd runs NB steps ----
    const int FAh = (lenA + 1) >> 1, FBh = (lenB + 1) >> 1;
    const int actA = isb ? (lenA - FAh) : (FAh - 1);
    const int actB = isb ? (lenB - FBh) : (FBh - 1);
    const int TRIP = actA > actB ? actA : actB;

    // ---- chain inits ----
    const int itA = isb ? (lenA - 1) : 0;
    const int itB = isb ? (lenB - 1) : 0;
    const float im = isb ? M2[23].x : M2[22].y;      // wave-uniform-select of lane reg
    float vA = __expf(frowA[(size_t)itA * Td + lidx]) * im;
    float vB = __expf(frowB[(size_t)itB * Td + lidx]) * im;
    float ufA = M2[23].x, ufB = M2[23].x;            // bwd NB==0 case: wstop
    int LA = 0, LB = 0;
    int kxA, kxB; float scA, scB;
    { int kb = rfl_i(__float_as_int(vA)); kxA = ((kb>>23)&0xFF)-127; scA = __int_as_float((127-kxA)<<23); }
    { int kb = rfl_i(__float_as_int(vB)); kxB = ((kb>>23)&0xFF)-127; scB = __int_as_float((127-kxB)<<23); }

    if (vlane) { vls[CH_A][lane] = vA; vls[CH_B][lane] = vB; }
    asm volatile("" ::: "memory");
    v4f rA[12], rB[12];
#pragma unroll
    for (int q = 0; q < 12; ++q) {
        rA[q] = ((const v4f*)vls[CH_A])[q];
        rB[q] = ((const v4f*)vls[CH_B])[q];
    }

    // ---- emission prefetch: 4 slots/chain; uniform pointers, scalar deltas ----
    auto eidx = [&](int s, int len, int Fh) {        // index consumed at superstep s
        if (!isb) { int t = s + 1; int hi = Fh - 1; return t < hi ? t : (hi < 0 ? 0 : hi); }
        int t = len - 2 - s; return t > 0 ? t : 0;
    };
    float pf0A = frowA[(size_t)eidx(0, lenA, FAh) * Td + lidx];
    float pf1A = frowA[(size_t)eidx(1, lenA, FAh) * Td + lidx];
    float pf2A = frowA[(size_t)eidx(2, lenA, FAh) * Td + lidx];
    float pf3A = frowA[(size_t)eidx(3, lenA, FAh) * Td + lidx];
    float pf0B = frowB[(size_t)eidx(0, lenB, FBh) * Td + lidx];
    float pf1B = frowB[(size_t)eidx(1, lenB, FBh) * Td + lidx];
    float pf2B = frowB[(size_t)eidx(2, lenB, FBh) * Td + lidx];
    float pf3B = frowB[(size_t)eidx(3, lenB, FBh) * Td + lidx];

    int tA = eidx(4, lenA, FAh), tB = eidx(4, lenB, FBh);
    const float* pA = frowA + (size_t)tA * Td;
    const float* pB = frowB + (size_t)tB * Td;
    const int hiA = FAh - 1, hiB = FBh - 1;          // fwd upper clamp
    const int sAdv = isb ? -Td : Td;                 // scalar pointer delta
    const int sInc = isb ? -1 : 1;

    int k = 0;
    while (k + 4 <= TRIP) {
        STEP_ONE(A, pf0A, k);     pf0A = pA[lidx]; ADV(A);
        STEP_ONE(B, pf0B, k);     pf0B = pB[lidx]; ADV(B);
        STEP_ONE(A, pf1A, k + 1); pf1A = pA[lidx]; ADV(A);
        STEP_ONE(B, pf1B, k + 1); pf1B = pB[lidx]; ADV(B);
        STEP_ONE(A, pf2A, k + 2); pf2A = pA[lidx]; ADV(A);
        STEP_ONE(B, pf2B, k + 2); pf2B = pB[lidx]; ADV(B);
        STEP_ONE(A, pf3A, k + 3); pf3A = pA[lidx]; ADV(A);
        STEP_ONE(B, pf3B, k + 3); pf3B = pB[lidx]; ADV(B);
        k += 4;
    }
    if (k < TRIP) { STEP_ONE(A, pf0A, k); STEP_ONE(B, pf0B, k); ++k; }
    if (k < TRIP) { STEP_ONE(A, pf1A, k); STEP_ONE(B, pf1B, k); ++k; }
    if (k < TRIP) { STEP_ONE(A, pf2A, k); STEP_ONE(B, pf2B, k); ++k; }

    // ---- publish meeting pieces (component-major for coalesced combine) ----
    if (!isb) {
        if (vlane) { wsv[lane * Bn + bA] = vA; wsv[lane * Bn + bB] = vB; }
        if (lane == 0) { wsLF[bA] = LA; wsLF[bB] = LB; }
    } else {
        if (vlane) { wsu[lane * Bn + bA] = ufA; wsu[lane * Bn + bB] = ufB; }
        if (lane == 0) { wsLB[bA] = LA; wsLB[bB] = LB; }
    }
}

__launch_bounds__(64)
__global__ void crf_combine(const float* __restrict__ wsv,
                            const float* __restrict__ wsu,
                            const int* __restrict__ wsLF,
                            const int* __restrict__ wsLB,
                            const float* __restrict__ wsg,
                            float* __restrict__ out, int Bn)
{
    const int b = blockIdx.x * 64 + threadIdx.x;
    if (b >= Bn) return;
    float dot = 0.f;
#pragma unroll
    for (int j = 0; j < Td; ++j)
        dot += wsv[j * Bn + b] * wsu[j * Bn + b];
    const float ln2 = 0.6931471805599453f;
    out[b] = (float)(wsLF[b] + wsLB[b]) * ln2 + __logf(dot) - wsg[b];
}

extern "C" void kernel_launch(void* const* d_in, const int* in_sizes, int n_in,
                              void* d_out, int out_size, void* d_ws, size_t ws_size,
                              hipStream_t stream) {
    const float* feats = (const float*)d_in[0];
    const float* masks = (const float*)d_in[1];
    const int*   tags  = (const int*)d_in[2];
    const float* trans = (const float*)d_in[3];
    float* outp = (float*)d_out;

    const int Bn = in_sizes[1] / Sd;                 // B = 512

    float* wsv  = (float*)d_ws;                      // [48][Bn]
    float* wsu  = wsv + (size_t)Td * Bn;             // [48][Bn]
    int*   wsLF = (int*)(wsu + (size_t)Td * Bn);     // [Bn]
    int*   wsLB = wsLF + Bn;                         // [Bn]
    float* wsg  = (float*)(wsLB + Bn);               // [Bn]

    crf_chains<<<dim3(Bn), dim3(64), 0, stream>>>(feats, masks, tags, trans,
                                                  wsv, wsu, wsLF, wsLB, wsg, Bn);
    crf_combine<<<dim3((Bn + 63) / 64), dim3(64), 0, stream>>>(wsv, wsu, wsLF, wsLB, wsg, outp, Bn);
}

// Round 9
// 161.039 us; speedup vs baseline: 1.6383x; 1.5754x over previous
//
#include <hip/hip_runtime.h>
#include <cstdint>

constexpr int Sd = 1024;
constexpr int Td = 48;
constexpr int NTAG = 45;    // normal tags 0..44
constexpr int START_ = 45;
constexpr int STOP_ = 46;

typedef float v2f __attribute__((ext_vector_type(2)));

__device__ __forceinline__ int rfl_i(int x) { return __builtin_amdgcn_readfirstlane(x); }

// rotate within 16-lane row by c (row_ror:c); direction d detected at runtime
#define ROTF(x, c) __int_as_float(__builtin_amdgcn_mov_dpp(__float_as_int(x), 0x120|(c), 0xF, 0xF, false))

// One exp-domain chain step, all-VALU allgather (no LDS round trip):
//   permlane32_swap(v,v) -> one reg dup(low32), one dup(high32) (which-is-which
//   detected at runtime via marker); 2x ds_swizzle(xor16) completes 4 row-copies;
//   60 DPP row_ror rotations expand to all 64 values; dot with epk (preloaded in
//   the matching per-lane permuted order); scalar power-of-2 renorm (R5-validated).
#define STEP1(PF) do {                                                         \
    float _e = __expf(PF);                                                     \
    int _a = __float_as_int(v), _b = __float_as_int(v);                        \
    asm("v_permlane32_swap_b32 %0, %1" : "+v"(_a), "+v"(_b));                  \
    int _c2 = __builtin_amdgcn_ds_swizzle(_b, 0x401F);  /* xor16 */            \
    int _c3 = __builtin_amdgcn_ds_swizzle(_a, 0x401F);                         \
    float gvx[4][16];                                                          \
    gvx[0][0] = __int_as_float(_b);                                            \
    gvx[1][0] = __int_as_float(_a);                                            \
    gvx[2][0] = __int_as_float(_c2);                                           \
    gvx[3][0] = __int_as_float(_c3);                                           \
    _Pragma("unroll")                                                          \
    for (int h_ = 0; h_ < 4; ++h_) {                                           \
        gvx[h_][1] = ROTF(gvx[h_][0], 1);                                      \
        gvx[h_][2] = ROTF(gvx[h_][0], 2);                                      \
        gvx[h_][3] = ROTF(gvx[h_][1], 2);                                      \
        _Pragma("unroll")                                                      \
        for (int i_ = 0; i_ < 4; ++i_) gvx[h_][4+i_] = ROTF(gvx[h_][i_], 4);   \
        _Pragma("unroll")                                                      \
        for (int i_ = 0; i_ < 8; ++i_) gvx[h_][8+i_] = ROTF(gvx[h_][i_], 8);   \
    }                                                                          \
    v2f _ac0={0.f,0.f}, _ac1={0.f,0.f}, _ac2={0.f,0.f}, _ac3={0.f,0.f};        \
    _Pragma("unroll")                                                          \
    for (int j_ = 0; j_ < 8; ++j_) {                                           \
        v2f _g0 = { gvx[0][2*j_], gvx[0][2*j_+1] };                            \
        v2f _g1 = { gvx[1][2*j_], gvx[1][2*j_+1] };                            \
        v2f _g2 = { gvx[2][2*j_], gvx[2][2*j_+1] };                            \
        v2f _g3 = { gvx[3][2*j_], gvx[3][2*j_+1] };                            \
        _ac0 = __builtin_elementwise_fma(epk[0][j_], _g0, _ac0);               \
        _ac1 = __builtin_elementwise_fma(epk[1][j_], _g1, _ac1);               \
        _ac2 = __builtin_elementwise_fma(epk[2][j_], _g2, _ac2);               \
        _ac3 = __builtin_elementwise_fma(epk[3][j_], _g3, _ac3);               \
    }                                                                          \
    v2f _s = (_ac0 + _ac1) + (_ac2 + _ac3);                                    \
    float tot_ = _s.x + _s.y;                                                  \
    L += kx;                                                                   \
    uf = tot_ * sc;                                                            \
    v  = tot_ * (_e * sc);                                                     \
    { int _kb = rfl_i(__float_as_int(v));                                      \
      kx = ((_kb >> 23) & 0xFF) - 127;                                         \
      sc = __int_as_float((127 - kx) << 23); }                                 \
} while (0)

#define ADVP() do {                                                            \
    bool ok_ = isb ? (tn > 0) : (tn < tmax);                                   \
    pcur += ok_ ? sAdv : 0;                                                    \
    tn   += ok_ ? sInc : 0;                                                    \
} while (0)

__launch_bounds__(64, 1)
__global__ void crf_chains(const float* __restrict__ feats,
                           const float* __restrict__ masks,
                           const int* __restrict__ tags,
                           const float* __restrict__ trans,
                           float* __restrict__ wsv,   // [48][Bn] fwd meeting vec
                           float* __restrict__ wsu,   // [48][Bn] bwd meeting vec
                           int* __restrict__ wsLF, int* __restrict__ wsLB,
                           float* __restrict__ wsg,   // [Bn] gold
                           int Bn)
{
    __shared__ float tl[Td * Td];
    const int lane = threadIdx.x;
    const bool isb = ((int)blockIdx.x >= Bn);        // block-uniform direction
    const int b = isb ? ((int)blockIdx.x - Bn) : (int)blockIdx.x;

    for (int i = lane; i < Td * Td; i += 64) tl[i] = trans[i];
    __syncthreads();

    const size_t bS = (size_t)b * Sd;

    // ---- length from prefix mask (scalar) ----
    float c = 0.f;
    for (int t = lane; t < Sd; t += 64) c += masks[bS + t];
#pragma unroll
    for (int off = 32; off; off >>= 1) c += __shfl_xor(c, off);
    int len = (int)(c + 0.5f);
    if (len < 1) len = 1;
    len = rfl_i(len);

    // ---- gold score (fwd blocks only) ----
    if (!isb) {
        float g = 0.f;
        for (int t = lane; t < len; t += 64) {
            const int tag  = tags[bS + t];
            const int prev = (t == 0) ? START_ : tags[bS + t - 1];
            g += feats[(bS + t) * Td + tag] + tl[tag * Td + prev];
        }
#pragma unroll
        for (int off = 32; off; off >>= 1) g += __shfl_xor(g, off);
        g += tl[STOP_ * Td + tags[bS + len - 1]];
        if (lane == 0) wsg[b] = g;
    }

    // ---- runtime-detect BOTH gather semantics (zero assumptions) ----
    // (1) row_ror direction
    const int p = lane & 15;
    const int qd = __builtin_amdgcn_mov_dpp(p, 0x121, 0xF, 0xF, false); // row_ror:1
    const int d = (qd == ((p + 1) & 15)) ? 1 : -1;
    // (2) permlane32_swap half assignment: marker = lane index
    int ma = lane, mb = lane;
    asm("v_permlane32_swap_b32 %0, %1" : "+v"(ma), "+v"(mb));
    const bool aHigh = (rfl_i(ma) >= 32);            // does _a hold dup(high32)?
    const int b4 = (lane >> 4) & 1;
    int rowh[4];                                     // 16-row index per gather copy
    if (aHigh) {       // _b = dup(low), _a = dup(high)
        rowh[0] = b4;          rowh[1] = 2 + b4;
        rowh[2] = b4 ^ 1;      rowh[3] = 2 + (b4 ^ 1);
    } else {           // _a = dup(low), _b = dup(high)
        rowh[0] = 2 + b4;      rowh[1] = b4;
        rowh[2] = 2 + (b4 ^ 1); rowh[3] = b4 ^ 1;
    }

    // ---- E (fwd) / E^T (bwd) preloaded in per-lane gather-permuted order ----
    v2f epk[4][8];
#pragma unroll
    for (int h = 0; h < 4; ++h) {
#pragma unroll
        for (int j = 0; j < 8; ++j) {
            const int c0 = 16 * rowh[h] + ((p + d * (2 * j))     & 15);
            const int c1 = 16 * rowh[h] + ((p + d * (2 * j + 1)) & 15);
            float e0 = 0.f, e1 = 0.f;
            if (!isb) {
                if (lane < NTAG) {   // fwd rows >= 45 are sinks (exact)
                    e0 = (c0 < Td) ? __expf(tl[lane * Td + c0]) : 0.f;
                    e1 = (c1 < Td) ? __expf(tl[lane * Td + c1]) : 0.f;
                }
            } else {
                if (lane < Td) {
                    e0 = (c0 < Td) ? __expf(tl[c0 * Td + lane]) : 0.f;
                    e1 = (c1 < Td) ? __expf(tl[c1 * Td + lane]) : 0.f;
                }
            }
            v2f ee = { e0, e1 };
            epk[h][j] = ee;
        }
    }

    // ---- chain init ----
    const int lidx = (lane < Td) ? lane : 0;
    const float* frow = feats + bS * Sd / Sd * Td;   // = feats + bS*Td
    const int Fh = (len + 1) >> 1;
    const int act = rfl_i(isb ? (len - Fh) : (Fh - 1));
    const int it0 = isb ? (len - 1) : 0;

    float einit;
    if (!isb) einit = (lane < NTAG) ? __expf(tl[lane * Td + START_]) : 0.f;
    else      einit = (lane < Td)   ? __expf(tl[STOP_ * Td + lane])  : 0.f;

    float v  = __expf(frow[(size_t)it0 * Td + lidx]) * einit;
    float uf = einit;                 // bwd act==0 case: wstop
    int L = 0, kx; float sc;
    { int kb = rfl_i(__float_as_int(v)); kx = ((kb >> 23) & 0xFF) - 127;
      sc = __int_as_float((127 - kx) << 23); }

    // ---- emission prefetch: 8 slots, uniform pointer + scalar advance ----
    auto eidx0 = [&](int s) -> int {
        if (!isb) { int t = 1 + s; return t < Sd ? t : (Sd - 1); }
        int t = len - 2 - s; return t > 0 ? t : 0;
    };
    float pf0 = frow[(size_t)eidx0(0) * Td + lidx];
    float pf1 = frow[(size_t)eidx0(1) * Td + lidx];
    float pf2 = frow[(size_t)eidx0(2) * Td + lidx];
    float pf3 = frow[(size_t)eidx0(3) * Td + lidx];
    float pf4 = frow[(size_t)eidx0(4) * Td + lidx];
    float pf5 = frow[(size_t)eidx0(5) * Td + lidx];
    float pf6 = frow[(size_t)eidx0(6) * Td + lidx];
    float pf7 = frow[(size_t)eidx0(7) * Td + lidx];
    int tn = eidx0(8);
    const float* pcur = frow + (size_t)tn * Td;
    const int sAdv = isb ? -Td : Td;
    const int sInc = isb ? -1 : 1;
    const int tmax = Sd - 1;

    int s = 0;
    while (s + 8 <= act) {
        STEP1(pf0); pf0 = pcur[lidx]; ADVP();
        STEP1(pf1); pf1 = pcur[lidx]; ADVP();
        STEP1(pf2); pf2 = pcur[lidx]; ADVP();
        STEP1(pf3); pf3 = pcur[lidx]; ADVP();
        STEP1(pf4); pf4 = pcur[lidx]; ADVP();
        STEP1(pf5); pf5 = pcur[lidx]; ADVP();
        STEP1(pf6); pf6 = pcur[lidx]; ADVP();
        STEP1(pf7); pf7 = pcur[lidx]; ADVP();
        s += 8;
    }
    if (s < act) { STEP1(pf0); ++s; }
    if (s < act) { STEP1(pf1); ++s; }
    if (s < act) { STEP1(pf2); ++s; }
    if (s < act) { STEP1(pf3); ++s; }
    if (s < act) { STEP1(pf4); ++s; }
    if (s < act) { STEP1(pf5); ++s; }
    if (s < act) { STEP1(pf6); ++s; }

    // ---- publish meeting pieces (component-major for coalesced combine) ----
    if (!isb) {
        if (lane < Td) wsv[lane * Bn + b] = v;
        if (lane == 0) wsLF[b] = L;
    } else {
        if (lane < Td) wsu[lane * Bn + b] = uf;
        if (lane == 0) wsLB[b] = L;
    }
}

__launch_bounds__(64)
__global__ void crf_combine(const float* __restrict__ wsv,
                            const float* __restrict__ wsu,
                            const int* __restrict__ wsLF,
                            const int* __restrict__ wsLB,
                            const float* __restrict__ wsg,
                            float* __restrict__ out, int Bn)
{
    const int b = blockIdx.x * 64 + threadIdx.x;
    if (b >= Bn) return;
    float dot = 0.f;
#pragma unroll
    for (int j = 0; j < Td; ++j)
        dot += wsv[j * Bn + b] * wsu[j * Bn + b];
    const float ln2 = 0.6931471805599453f;
    out[b] = (float)(wsLF[b] + wsLB[b]) * ln2 + __logf(dot) - wsg[b];
}

extern "C" void kernel_launch(void* const* d_in, const int* in_sizes, int n_in,
                              void* d_out, int out_size, void* d_ws, size_t ws_size,
                              hipStream_t stream) {
    const float* feats = (const float*)d_in[0];
    const float* masks = (const float*)d_in[1];
    const int*   tags  = (const int*)d_in[2];
    const float* trans = (const float*)d_in[3];
    float* outp = (float*)d_out;

    const int Bn = in_sizes[1] / Sd;                 // B = 512

    float* wsv  = (float*)d_ws;                      // [48][Bn]
    float* wsu  = wsv + (size_t)Td * Bn;             // [48][Bn]
    int*   wsLF = (int*)(wsu + (size_t)Td * Bn);     // [Bn]
    int*   wsLB = wsLF + Bn;                         // [Bn]
    float* wsg  = (float*)(wsLB + Bn);               // [Bn]

    crf_chains<<<dim3(2 * Bn), dim3(64), 0, stream>>>(feats, masks, tags, trans,
                                                      wsv, wsu, wsLF, wsLB, wsg, Bn);
    crf_combine<<<dim3((Bn + 63) / 64), dim3(64), 0, stream>>>(wsv, wsu, wsLF, wsLB, wsg, outp, Bn);
}

// Round 10
// 159.896 us; speedup vs baseline: 1.6500x; 1.0071x over previous
//
#include <hip/hip_runtime.h>
#include <cstdint>

constexpr int Sd = 1024;
constexpr int Td = 48;
constexpr int NTAG = 45;    // normal tags 0..44
constexpr int START_ = 45;
constexpr int STOP_ = 46;

typedef float v2f __attribute__((ext_vector_type(2)));

__device__ __forceinline__ int rfl_i(int x) { return __builtin_amdgcn_readfirstlane(x); }

// rotate within 16-lane row by c (row_ror:c); direction d detected at runtime
#define ROTF(x, c) __int_as_float(__builtin_amdgcn_mov_dpp(__float_as_int(x), 0x120|(c), 0xF, 0xF, false))

// One exp-domain chain step, 100% VALU allgather (no LDS-pipe ops at all):
//   swap32(v,v) -> dup(lo32), dup(hi32); swap16 self on each -> four uniform
//   16-periodic regs (one per 16-row of v; row->slot map runtime-detected);
//   60 DPP row_ror rotations expand to all 64 values; dot with epk (preloaded
//   in matching permuted order); scalar power-of-2 renorm (R5/R9-validated).
#define STEP1(PF) do {                                                         \
    float _e = __expf(PF);                                                     \
    int _a = __float_as_int(v), _b = __float_as_int(v);                        \
    asm("v_permlane32_swap_b32 %0, %1" : "+v"(_a), "+v"(_b));                  \
    int _s0 = _a, _s1 = _a, _s2 = _b, _s3 = _b;                                \
    asm("v_permlane16_swap_b32 %0, %1" : "+v"(_s0), "+v"(_s1));                \
    asm("v_permlane16_swap_b32 %0, %1" : "+v"(_s2), "+v"(_s3));                \
    float gvx[4][16];                                                          \
    gvx[0][0] = __int_as_float(_s0);                                           \
    gvx[1][0] = __int_as_float(_s1);                                           \
    gvx[2][0] = __int_as_float(_s2);                                           \
    gvx[3][0] = __int_as_float(_s3);                                           \
    _Pragma("unroll")                                                          \
    for (int h_ = 0; h_ < 4; ++h_) {                                           \
        gvx[h_][1] = ROTF(gvx[h_][0], 1);                                      \
        gvx[h_][2] = ROTF(gvx[h_][0], 2);                                      \
        gvx[h_][3] = ROTF(gvx[h_][1], 2);                                      \
        _Pragma("unroll")                                                      \
        for (int i_ = 0; i_ < 4; ++i_) gvx[h_][4+i_] = ROTF(gvx[h_][i_], 4);   \
        _Pragma("unroll")                                                      \
        for (int i_ = 0; i_ < 8; ++i_) gvx[h_][8+i_] = ROTF(gvx[h_][i_], 8);   \
    }                                                                          \
    v2f _ac0={0.f,0.f}, _ac1={0.f,0.f}, _ac2={0.f,0.f}, _ac3={0.f,0.f};        \
    _Pragma("unroll")                                                          \
    for (int j_ = 0; j_ < 8; ++j_) {                                           \
        v2f _g0 = { gvx[0][2*j_], gvx[0][2*j_+1] };                            \
        v2f _g1 = { gvx[1][2*j_], gvx[1][2*j_+1] };                            \
        v2f _g2 = { gvx[2][2*j_], gvx[2][2*j_+1] };                            \
        v2f _g3 = { gvx[3][2*j_], gvx[3][2*j_+1] };                            \
        _ac0 = __builtin_elementwise_fma(epk[0][j_], _g0, _ac0);               \
        _ac1 = __builtin_elementwise_fma(epk[1][j_], _g1, _ac1);               \
        _ac2 = __builtin_elementwise_fma(epk[2][j_], _g2, _ac2);               \
        _ac3 = __builtin_elementwise_fma(epk[3][j_], _g3, _ac3);               \
    }                                                                          \
    v2f _s = (_ac0 + _ac1) + (_ac2 + _ac3);                                    \
    float tot_ = _s.x + _s.y;                                                  \
    L += kx;                                                                   \
    uf = tot_ * sc;                                                            \
    v  = tot_ * (_e * sc);                                                     \
    { int _kb = rfl_i(__float_as_int(v));                                      \
      kx = ((_kb >> 23) & 0xFF) - 127;                                         \
      sc = __int_as_float((127 - kx) << 23); }                                 \
} while (0)

#define ADVP() do {                                                            \
    bool ok_ = isb ? (tn > 0) : (tn < tmax);                                   \
    pcur += ok_ ? sAdv : 0;                                                    \
    tn   += ok_ ? sInc : 0;                                                    \
} while (0)

__launch_bounds__(64, 1)
__global__ void crf_chains(const float* __restrict__ feats,
                           const float* __restrict__ masks,
                           const int* __restrict__ tags,
                           const float* __restrict__ trans,
                           float* __restrict__ wsv,   // [48][Bn] fwd meeting vec
                           float* __restrict__ wsu,   // [48][Bn] bwd meeting vec
                           int* __restrict__ wsLF, int* __restrict__ wsLB,
                           float* __restrict__ wsg,   // [Bn] gold
                           int Bn)
{
    __shared__ float tl[Td * Td];
    const int lane = threadIdx.x;
    const bool isb = ((int)blockIdx.x >= Bn);        // block-uniform direction
    const int b = isb ? ((int)blockIdx.x - Bn) : (int)blockIdx.x;

    for (int i = lane; i < Td * Td; i += 64) tl[i] = trans[i];
    __syncthreads();

    const size_t bS = (size_t)b * Sd;

    // ---- length from prefix mask (scalar) ----
    float c = 0.f;
    for (int t = lane; t < Sd; t += 64) c += masks[bS + t];
#pragma unroll
    for (int off = 32; off; off >>= 1) c += __shfl_xor(c, off);
    int len = (int)(c + 0.5f);
    if (len < 1) len = 1;
    len = rfl_i(len);

    // ---- gold score (fwd blocks only) ----
    if (!isb) {
        float g = 0.f;
        for (int t = lane; t < len; t += 64) {
            const int tag  = tags[bS + t];
            const int prev = (t == 0) ? START_ : tags[bS + t - 1];
            g += feats[(bS + t) * Td + tag] + tl[tag * Td + prev];
        }
#pragma unroll
        for (int off = 32; off; off >>= 1) g += __shfl_xor(g, off);
        g += tl[STOP_ * Td + tags[bS + len - 1]];
        if (lane == 0) wsg[b] = g;
    }

    // ---- runtime-detect gather semantics (zero assumptions) ----
    // (1) row_ror direction
    const int p = lane & 15;
    const int qd = __builtin_amdgcn_mov_dpp(p, 0x121, 0xF, 0xF, false); // row_ror:1
    const int d = (qd == ((p + 1) & 15)) ? 1 : -1;
    // (2) full slot->16-row map: push marker (=lane) through the swap pipeline
    int ma = lane, mb = lane;
    asm("v_permlane32_swap_b32 %0, %1" : "+v"(ma), "+v"(mb));
    int m0 = ma, m1 = ma, m2 = mb, m3 = mb;
    asm("v_permlane16_swap_b32 %0, %1" : "+v"(m0), "+v"(m1));
    asm("v_permlane16_swap_b32 %0, %1" : "+v"(m2), "+v"(m3));
    int rowOf[4];
    rowOf[0] = rfl_i(m0) >> 4;
    rowOf[1] = rfl_i(m1) >> 4;
    rowOf[2] = rfl_i(m2) >> 4;
    rowOf[3] = rfl_i(m3) >> 4;

    // ---- E (fwd) / E^T (bwd) preloaded in per-lane gather-permuted order ----
    v2f epk[4][8];
#pragma unroll
    for (int h = 0; h < 4; ++h) {
#pragma unroll
        for (int j = 0; j < 8; ++j) {
            const int c0 = 16 * rowOf[h] + ((p + d * (2 * j))     & 15);
            const int c1 = 16 * rowOf[h] + ((p + d * (2 * j + 1)) & 15);
            float e0 = 0.f, e1 = 0.f;
            if (!isb) {
                if (lane < NTAG) {   // fwd rows >= 45 are exact sinks
                    e0 = (c0 < Td) ? __expf(tl[lane * Td + c0]) : 0.f;
                    e1 = (c1 < Td) ? __expf(tl[lane * Td + c1]) : 0.f;
                }
            } else {
                if (lane < Td) {
                    e0 = (c0 < Td) ? __expf(tl[c0 * Td + lane]) : 0.f;
                    e1 = (c1 < Td) ? __expf(tl[c1 * Td + lane]) : 0.f;
                }
            }
            v2f ee = { e0, e1 };
            epk[h][j] = ee;
        }
    }

    // ---- chain init ----
    const int lidx = (lane < Td) ? lane : 0;
    const float* frow = feats + bS * Td;
    const int Fh = (len + 1) >> 1;
    const int act = rfl_i(isb ? (len - Fh) : (Fh - 1));
    const int it0 = isb ? (len - 1) : 0;

    float einit;
    if (!isb) einit = (lane < NTAG) ? __expf(tl[lane * Td + START_]) : 0.f;
    else      einit = (lane < Td)   ? __expf(tl[STOP_ * Td + lane])  : 0.f;

    float v  = __expf(frow[(size_t)it0 * Td + lidx]) * einit;
    float uf = einit;                 // bwd act==0 case: wstop
    int L = 0, kx; float sc;
    { int kb = rfl_i(__float_as_int(v)); kx = ((kb >> 23) & 0xFF) - 127;
      sc = __int_as_float((127 - kx) << 23); }

    // ---- emission prefetch: 8 slots, uniform pointer + scalar advance ----
    auto eidx0 = [&](int s) -> int {
        if (!isb) { int t = 1 + s; return t < Sd ? t : (Sd - 1); }
        int t = len - 2 - s; return t > 0 ? t : 0;
    };
    float pf0 = frow[(size_t)eidx0(0) * Td + lidx];
    float pf1 = frow[(size_t)eidx0(1) * Td + lidx];
    float pf2 = frow[(size_t)eidx0(2) * Td + lidx];
    float pf3 = frow[(size_t)eidx0(3) * Td + lidx];
    float pf4 = frow[(size_t)eidx0(4) * Td + lidx];
    float pf5 = frow[(size_t)eidx0(5) * Td + lidx];
    float pf6 = frow[(size_t)eidx0(6) * Td + lidx];
    float pf7 = frow[(size_t)eidx0(7) * Td + lidx];
    int tn = eidx0(8);
    const float* pcur = frow + (size_t)tn * Td;
    const int sAdv = isb ? -Td : Td;
    const int sInc = isb ? -1 : 1;
    const int tmax = Sd - 1;

    int s = 0;
    while (s + 8 <= act) {
        STEP1(pf0); pf0 = pcur[lidx]; ADVP();
        STEP1(pf1); pf1 = pcur[lidx]; ADVP();
        STEP1(pf2); pf2 = pcur[lidx]; ADVP();
        STEP1(pf3); pf3 = pcur[lidx]; ADVP();
        STEP1(pf4); pf4 = pcur[lidx]; ADVP();
        STEP1(pf5); pf5 = pcur[lidx]; ADVP();
        STEP1(pf6); pf6 = pcur[lidx]; ADVP();
        STEP1(pf7); pf7 = pcur[lidx]; ADVP();
        s += 8;
    }
    if (s < act) { STEP1(pf0); ++s; }
    if (s < act) { STEP1(pf1); ++s; }
    if (s < act) { STEP1(pf2); ++s; }
    if (s < act) { STEP1(pf3); ++s; }
    if (s < act) { STEP1(pf4); ++s; }
    if (s < act) { STEP1(pf5); ++s; }
    if (s < act) { STEP1(pf6); ++s; }

    // ---- publish meeting pieces (component-major for coalesced combine) ----
    if (!isb) {
        if (lane < Td) wsv[lane * Bn + b] = v;
        if (lane == 0) wsLF[b] = L;
    } else {
        if (lane < Td) wsu[lane * Bn + b] = uf;
        if (lane == 0) wsLB[b] = L;
    }
}

__launch_bounds__(64)
__global__ void crf_combine(const float* __restrict__ wsv,
                            const float* __restrict__ wsu,
                            const int* __restrict__ wsLF,
                            const int* __restrict__ wsLB,
                            const float* __restrict__ wsg,
                            float* __restrict__ out, int Bn)
{
    const int b = blockIdx.x * 64 + threadIdx.x;
    if (b >= Bn) return;
    float dot = 0.f;
#pragma unroll
    for (int j = 0; j < Td; ++j)
        dot += wsv[j * Bn + b] * wsu[j * Bn + b];
    const float ln2 = 0.6931471805599453f;
    out[b] = (float)(wsLF[b] + wsLB[b]) * ln2 + __logf(dot) - wsg[b];
}

extern "C" void kernel_launch(void* const* d_in, const int* in_sizes, int n_in,
                              void* d_out, int out_size, void* d_ws, size_t ws_size,
                              hipStream_t stream) {
    const float* feats = (const float*)d_in[0];
    const float* masks = (const float*)d_in[1];
    const int*   tags  = (const int*)d_in[2];
    const float* trans = (const float*)d_in[3];
    float* outp = (float*)d_out;

    const int Bn = in_sizes[1] / Sd;                 // B = 512

    float* wsv  = (float*)d_ws;                      // [48][Bn]
    float* wsu  = wsv + (size_t)Td * Bn;             // [48][Bn]
    int*   wsLF = (int*)(wsu + (size_t)Td * Bn);     // [Bn]
    int*   wsLB = wsLF + Bn;                         // [Bn]
    float* wsg  = (float*)(wsLB + Bn);               // [Bn]

    crf_chains<<<dim3(2 * Bn), dim3(64), 0, stream>>>(feats, masks, tags, trans,
                                                      wsv, wsu, wsLF, wsLB, wsg, Bn);
    crf_combine<<<dim3((Bn + 63) / 64), dim3(64), 0, stream>>>(wsv, wsu, wsLF, wsLB, wsg, outp, Bn);
}

// Round 11
// 131.541 us; speedup vs baseline: 2.0057x; 1.2156x over previous
//
#include <hip/hip_runtime.h>
#include <cstdint>

constexpr int Sd = 1024;
constexpr int Td = 48;
constexpr int NTAG = 45;    // normal tags 0..44
constexpr int START_ = 45;
constexpr int STOP_ = 46;

typedef float v2f __attribute__((ext_vector_type(2)));

__device__ __forceinline__ int rfl_i(int x) { return __builtin_amdgcn_readfirstlane(x); }

// rotate within 16-lane row by c (row_ror:c); direction d detected at runtime
#define ROTF(x, c) __int_as_float(__builtin_amdgcn_mov_dpp(__float_as_int(x), 0x120|(c), 0xF, 0xF, false))

// One exp-domain chain step, 48-column gather (3 slots, ~80 instrs):
//   slot0 = v (own 16-block); slot1/2 = ds_bpermute v[(lane+16/32)%48]
//   (static semantics: pull from lane addr>>2). Each slot expands to 16
//   rotations via DPP row_ror; dot with epk[3][8] (preloaded in matching
//   permuted order); scalar power-of-2 renorm (R5/R9/R10-validated).
#define STEP1(PF) do {                                                         \
    int _vi = __float_as_int(v);                                               \
    int _b1 = __builtin_amdgcn_ds_bpermute(a16, _vi);                          \
    int _b2 = __builtin_amdgcn_ds_bpermute(a32, _vi);                          \
    float _e = __expf(PF);                                                     \
    float g0v[16], g1v[16], g2v[16];                                           \
    g0v[0] = v;                                                                \
    g0v[1] = ROTF(g0v[0], 1);                                                  \
    g0v[2] = ROTF(g0v[0], 2);                                                  \
    g0v[3] = ROTF(g0v[1], 2);                                                  \
    _Pragma("unroll")                                                          \
    for (int i_ = 0; i_ < 4; ++i_) g0v[4+i_] = ROTF(g0v[i_], 4);               \
    _Pragma("unroll")                                                          \
    for (int i_ = 0; i_ < 8; ++i_) g0v[8+i_] = ROTF(g0v[i_], 8);               \
    g1v[0] = __int_as_float(_b1);                                              \
    g1v[1] = ROTF(g1v[0], 1);                                                  \
    g1v[2] = ROTF(g1v[0], 2);                                                  \
    g1v[3] = ROTF(g1v[1], 2);                                                  \
    _Pragma("unroll")                                                          \
    for (int i_ = 0; i_ < 4; ++i_) g1v[4+i_] = ROTF(g1v[i_], 4);               \
    _Pragma("unroll")                                                          \
    for (int i_ = 0; i_ < 8; ++i_) g1v[8+i_] = ROTF(g1v[i_], 8);               \
    g2v[0] = __int_as_float(_b2);                                              \
    g2v[1] = ROTF(g2v[0], 1);                                                  \
    g2v[2] = ROTF(g2v[0], 2);                                                  \
    g2v[3] = ROTF(g2v[1], 2);                                                  \
    _Pragma("unroll")                                                          \
    for (int i_ = 0; i_ < 4; ++i_) g2v[4+i_] = ROTF(g2v[i_], 4);               \
    _Pragma("unroll")                                                          \
    for (int i_ = 0; i_ < 8; ++i_) g2v[8+i_] = ROTF(g2v[i_], 8);               \
    v2f _ac0={0.f,0.f}, _ac1={0.f,0.f}, _ac2={0.f,0.f};                        \
    _Pragma("unroll")                                                          \
    for (int j_ = 0; j_ < 8; ++j_) {                                           \
        v2f _g0 = { g0v[2*j_], g0v[2*j_+1] };                                  \
        v2f _g1 = { g1v[2*j_], g1v[2*j_+1] };                                  \
        v2f _g2 = { g2v[2*j_], g2v[2*j_+1] };                                  \
        _ac0 = __builtin_elementwise_fma(epk[0][j_], _g0, _ac0);               \
        _ac1 = __builtin_elementwise_fma(epk[1][j_], _g1, _ac1);               \
        _ac2 = __builtin_elementwise_fma(epk[2][j_], _g2, _ac2);               \
    }                                                                          \
    v2f _s = _ac0 + (_ac1 + _ac2);                                             \
    float tot_ = _s.x + _s.y;                                                  \
    L += kx;                                                                   \
    uf = tot_ * sc;                                                            \
    v  = tot_ * (_e * sc);                                                     \
    { int _kb = rfl_i(__float_as_int(v));                                      \
      kx = ((_kb >> 23) & 0xFF) - 127;                                         \
      sc = __int_as_float((127 - kx) << 23); }                                 \
} while (0)

#define ADVP() do {                                                            \
    bool ok_ = isb ? (tn > 0) : (tn < tmax);                                   \
    pcur += ok_ ? sAdv : 0;                                                    \
    tn   += ok_ ? sInc : 0;                                                    \
} while (0)

__launch_bounds__(64, 1)
__global__ void crf_chains(const float* __restrict__ feats,
                           const float* __restrict__ masks,
                           const int* __restrict__ tags,
                           const float* __restrict__ trans,
                           float* __restrict__ wsv,   // [48][Bn] fwd meeting vec
                           float* __restrict__ wsu,   // [48][Bn] bwd meeting vec
                           int* __restrict__ wsLF, int* __restrict__ wsLB,
                           float* __restrict__ wsg,   // [Bn] gold
                           int Bn)
{
    __shared__ float tl[Td * Td];
    const int lane = threadIdx.x;
    const bool isb = ((int)blockIdx.x >= Bn);        // block-uniform direction
    const int b = isb ? ((int)blockIdx.x - Bn) : (int)blockIdx.x;

    for (int i = lane; i < Td * Td; i += 64) tl[i] = trans[i];
    __syncthreads();

    const size_t bS = (size_t)b * Sd;

    // ---- length from prefix mask (scalar) ----
    float c = 0.f;
    for (int t = lane; t < Sd; t += 64) c += masks[bS + t];
#pragma unroll
    for (int off = 32; off; off >>= 1) c += __shfl_xor(c, off);
    int len = (int)(c + 0.5f);
    if (len < 1) len = 1;
    len = rfl_i(len);

    // ---- gold score (fwd blocks only) ----
    if (!isb) {
        float g = 0.f;
        for (int t = lane; t < len; t += 64) {
            const int tag  = tags[bS + t];
            const int prev = (t == 0) ? START_ : tags[bS + t - 1];
            g += feats[(bS + t) * Td + tag] + tl[tag * Td + prev];
        }
#pragma unroll
        for (int off = 32; off; off >>= 1) g += __shfl_xor(g, off);
        g += tl[STOP_ * Td + tags[bS + len - 1]];
        if (lane == 0) wsg[b] = g;
    }

    // ---- runtime-detect row_ror direction (validated in R9/R10) ----
    const int p = lane & 15;
    const int qd = __builtin_amdgcn_mov_dpp(p, 0x121, 0xF, 0xF, false); // row_ror:1
    const int d = (qd == ((p + 1) & 15)) ? 1 : -1;
    const int r0 = (lane >> 4) & 3;                  // own 16-block (3 = idle lanes)

    // ---- bpermute byte-addresses for the 3-block rotation gather ----
    const int a16 = (((lane + 16) % Td) << 2);       // pull v[(lane+16)%48]
    const int a32 = (((lane + 32) % Td) << 2);       // pull v[(lane+32)%48]

    // ---- E (fwd) / E^T (bwd) preloaded in gather-permuted order, 48 cols ----
    v2f epk[3][8];
#pragma unroll
    for (int h = 0; h < 3; ++h) {
        const int blk = 16 * ((r0 + h) % 3);
#pragma unroll
        for (int j = 0; j < 8; ++j) {
            const int c0 = blk + ((p + d * (2 * j))     & 15);
            const int c1 = blk + ((p + d * (2 * j + 1)) & 15);
            float e0 = 0.f, e1 = 0.f;
            if (!isb) {
                if (lane < NTAG) {   // fwd rows >= 45 are exact sinks
                    e0 = __expf(tl[lane * Td + c0]);
                    e1 = __expf(tl[lane * Td + c1]);
                }
            } else {
                if (lane < Td) {
                    e0 = __expf(tl[c0 * Td + lane]);
                    e1 = __expf(tl[c1 * Td + lane]);
                }
            }
            v2f ee = { e0, e1 };
            epk[h][j] = ee;
        }
    }

    // ---- chain init ----
    const int lidx = (lane < Td) ? lane : 0;
    const float* frow = feats + bS * Td;
    const int Fh = (len + 1) >> 1;
    const int act = rfl_i(isb ? (len - Fh) : (Fh - 1));
    const int it0 = isb ? (len - 1) : 0;

    float einit;
    if (!isb) einit = (lane < NTAG) ? __expf(tl[lane * Td + START_]) : 0.f;
    else      einit = (lane < Td)   ? __expf(tl[STOP_ * Td + lane])  : 0.f;

    float v  = __expf(frow[(size_t)it0 * Td + lidx]) * einit;
    float uf = einit;                 // bwd act==0 case: wstop
    int L = 0, kx; float sc;
    { int kb = rfl_i(__float_as_int(v)); kx = ((kb >> 23) & 0xFF) - 127;
      sc = __int_as_float((127 - kx) << 23); }

    // ---- emission prefetch: 8 slots, uniform pointer + scalar advance ----
    auto eidx0 = [&](int s) -> int {
        if (!isb) { int t = 1 + s; return t < Sd ? t : (Sd - 1); }
        int t = len - 2 - s; return t > 0 ? t : 0;
    };
    float pf0 = frow[(size_t)eidx0(0) * Td + lidx];
    float pf1 = frow[(size_t)eidx0(1) * Td + lidx];
    float pf2 = frow[(size_t)eidx0(2) * Td + lidx];
    float pf3 = frow[(size_t)eidx0(3) * Td + lidx];
    float pf4 = frow[(size_t)eidx0(4) * Td + lidx];
    float pf5 = frow[(size_t)eidx0(5) * Td + lidx];
    float pf6 = frow[(size_t)eidx0(6) * Td + lidx];
    float pf7 = frow[(size_t)eidx0(7) * Td + lidx];
    int tn = eidx0(8);
    const float* pcur = frow + (size_t)tn * Td;
    const int sAdv = isb ? -Td : Td;
    const int sInc = isb ? -1 : 1;
    const int tmax = Sd - 1;

    int s = 0;
    while (s + 8 <= act) {
        STEP1(pf0); pf0 = pcur[lidx]; ADVP();
        STEP1(pf1); pf1 = pcur[lidx]; ADVP();
        STEP1(pf2); pf2 = pcur[lidx]; ADVP();
        STEP1(pf3); pf3 = pcur[lidx]; ADVP();
        STEP1(pf4); pf4 = pcur[lidx]; ADVP();
        STEP1(pf5); pf5 = pcur[lidx]; ADVP();
        STEP1(pf6); pf6 = pcur[lidx]; ADVP();
        STEP1(pf7); pf7 = pcur[lidx]; ADVP();
        s += 8;
    }
    if (s < act) { STEP1(pf0); ++s; }
    if (s < act) { STEP1(pf1); ++s; }
    if (s < act) { STEP1(pf2); ++s; }
    if (s < act) { STEP1(pf3); ++s; }
    if (s < act) { STEP1(pf4); ++s; }
    if (s < act) { STEP1(pf5); ++s; }
    if (s < act) { STEP1(pf6); ++s; }

    // ---- publish meeting pieces (component-major for coalesced combine) ----
    if (!isb) {
        if (lane < Td) wsv[lane * Bn + b] = v;
        if (lane == 0) wsLF[b] = L;
    } else {
        if (lane < Td) wsu[lane * Bn + b] = uf;
        if (lane == 0) wsLB[b] = L;
    }
}

__launch_bounds__(64)
__global__ void crf_combine(const float* __restrict__ wsv,
                            const float* __restrict__ wsu,
                            const int* __restrict__ wsLF,
                            const int* __restrict__ wsLB,
                            const float* __restrict__ wsg,
                            float* __restrict__ out, int Bn)
{
    const int b = blockIdx.x * 64 + threadIdx.x;
    if (b >= Bn) return;
    float dot = 0.f;
#pragma unroll
    for (int j = 0; j < Td; ++j)
        dot += wsv[j * Bn + b] * wsu[j * Bn + b];
    const float ln2 = 0.6931471805599453f;
    out[b] = (float)(wsLF[b] + wsLB[b]) * ln2 + __logf(dot) - wsg[b];
}

extern "C" void kernel_launch(void* const* d_in, const int* in_sizes, int n_in,
                              void* d_out, int out_size, void* d_ws, size_t ws_size,
                              hipStream_t stream) {
    const float* feats = (const float*)d_in[0];
    const float* masks = (const float*)d_in[1];
    const int*   tags  = (const int*)d_in[2];
    const float* trans = (const float*)d_in[3];
    float* outp = (float*)d_out;

    const int Bn = in_sizes[1] / Sd;                 // B = 512

    float* wsv  = (float*)d_ws;                      // [48][Bn]
    float* wsu  = wsv + (size_t)Td * Bn;             // [48][Bn]
    int*   wsLF = (int*)(wsu + (size_t)Td * Bn);     // [Bn]
    int*   wsLB = wsLF + Bn;                         // [Bn]
    float* wsg  = (float*)(wsLB + Bn);               // [Bn]

    crf_chains<<<dim3(2 * Bn), dim3(64), 0, stream>>>(feats, masks, tags, trans,
                                                      wsv, wsu, wsLF, wsLB, wsg, Bn);
    crf_combine<<<dim3((Bn + 63) / 64), dim3(64), 0, stream>>>(wsv, wsu, wsLF, wsLB, wsg, outp, Bn);
}

// Round 12
// 119.062 us; speedup vs baseline: 2.2159x; 1.1048x over previous
//
#include <hip/hip_runtime.h>
#include <cstdint>

constexpr int Sd = 1024;
constexpr int Td = 48;
constexpr int NTAG = 45;    // normal tags 0..44
constexpr int START_ = 45;
constexpr int STOP_ = 46;

__device__ __forceinline__ int rfl_i(int x) { return __builtin_amdgcn_readfirstlane(x); }

// DPP-fused MAC: acc += rot(s, N) * ee   (rotation folded into the FMA)
#define FMD(acc, s, ee, N) \
    asm("v_fmac_f32 %0, %1, %2 row_ror:" #N " row_mask:0xf bank_mask:0xf" \
        : "+v"(acc) : "v"(s), "v"(ee))
// DPP-fused MUL (chain init): acc = rot(s, N) * ee
#define MULD(acc, s, ee, N) \
    asm("v_mul_f32 %0, %1, %2 row_ror:" #N " row_mask:0xf bank_mask:0xf" \
        : "=v"(acc) : "v"(s), "v"(ee))

// 16 rotations of one slot dotted with its E block; two 8-deep chains
#define SLOT16(s, E, aA, aB) do {                                              \
    aA = (s) * E[0];                                                           \
    FMD(aA, s, E[1], 1);  FMD(aA, s, E[2], 2);  FMD(aA, s, E[3], 3);           \
    FMD(aA, s, E[4], 4);  FMD(aA, s, E[5], 5);  FMD(aA, s, E[6], 6);           \
    FMD(aA, s, E[7], 7);                                                       \
    MULD(aB, s, E[8], 8);                                                      \
    FMD(aB, s, E[9], 9);  FMD(aB, s, E[10], 10); FMD(aB, s, E[11], 11);        \
    FMD(aB, s, E[12], 12); FMD(aB, s, E[13], 13); FMD(aB, s, E[14], 14);       \
    FMD(aB, s, E[15], 15);                                                     \
} while (0)

// One exp-domain chain step (~60 VALU):
//   slot0 = v; slot1/2 = ds_bpermute v[(lane+16/32)%48]  (R11-validated map)
//   48 DPP-fused MACs against eA0/eA1/eA2 (preloaded in permuted order)
//   PF holds PRE-EXP'd emission; scalar power-of-2 renorm (R5..R11-validated)
#define STEP1(PF) do {                                                         \
    int _vi = __float_as_int(v);                                               \
    int _b1 = __builtin_amdgcn_ds_bpermute(a16, _vi);                          \
    int _b2 = __builtin_amdgcn_ds_bpermute(a32, _vi);                          \
    float _s1 = __int_as_float(_b1), _s2 = __int_as_float(_b2);                \
    float a0A, a0B, a1A, a1B, a2A, a2B;                                        \
    SLOT16(v,   eA0, a0A, a0B);                                                \
    SLOT16(_s1, eA1, a1A, a1B);                                                \
    SLOT16(_s2, eA2, a2A, a2B);                                                \
    float tot_ = ((a0A + a0B) + (a1A + a1B)) + (a2A + a2B);                    \
    L += kx;                                                                   \
    uf = tot_ * sc;                                                            \
    v  = tot_ * ((PF) * sc);                                                   \
    { int _kb = rfl_i(__float_as_int(v));                                      \
      kx = ((_kb >> 23) & 0xFF) - 127;                                         \
      sc = __int_as_float((127 - kx) << 23); }                                 \
} while (0)

#define ADVP() do {                                                            \
    bool ok_ = isb ? (tn > 0) : (tn < tmax);                                   \
    pcur += ok_ ? sAdv : 0;                                                    \
    tn   += ok_ ? sInc : 0;                                                    \
} while (0)

__launch_bounds__(64, 1)
__global__ void crf_chains(const float* __restrict__ feats,
                           const float* __restrict__ masks,
                           const int* __restrict__ tags,
                           const float* __restrict__ trans,
                           float* __restrict__ wsv,   // [48][Bn] fwd meeting vec
                           float* __restrict__ wsu,   // [48][Bn] bwd meeting vec
                           int* __restrict__ wsLF, int* __restrict__ wsLB,
                           float* __restrict__ wsg,   // [Bn] gold
                           int Bn)
{
    __shared__ float tl[Td * Td];
    const int lane = threadIdx.x;
    const bool isb = ((int)blockIdx.x >= Bn);        // block-uniform direction
    const int b = isb ? ((int)blockIdx.x - Bn) : (int)blockIdx.x;

    for (int i = lane; i < Td * Td; i += 64) tl[i] = trans[i];
    __syncthreads();

    const size_t bS = (size_t)b * Sd;

    // ---- length from prefix mask (scalar) ----
    float c = 0.f;
    for (int t = lane; t < Sd; t += 64) c += masks[bS + t];
#pragma unroll
    for (int off = 32; off; off >>= 1) c += __shfl_xor(c, off);
    int len = (int)(c + 0.5f);
    if (len < 1) len = 1;
    len = rfl_i(len);

    // ---- gold score (fwd blocks only) ----
    if (!isb) {
        float g = 0.f;
        for (int t = lane; t < len; t += 64) {
            const int tag  = tags[bS + t];
            const int prev = (t == 0) ? START_ : tags[bS + t - 1];
            g += feats[(bS + t) * Td + tag] + tl[tag * Td + prev];
        }
#pragma unroll
        for (int off = 32; off; off >>= 1) g += __shfl_xor(g, off);
        g += tl[STOP_ * Td + tags[bS + len - 1]];
        if (lane == 0) wsg[b] = g;
    }

    // ---- runtime-detect row_ror direction (validated R9-R11) ----
    const int p = lane & 15;
    const int qd = __builtin_amdgcn_mov_dpp(p, 0x121, 0xF, 0xF, false); // row_ror:1
    const int d = (qd == ((p + 1) & 15)) ? 1 : -1;
    const int r0 = (lane >> 4) & 3;                  // own 16-block (3 = idle lanes)

    // ---- bpermute byte-addresses for the 3-block rotation gather ----
    const int a16 = (((lane + 16) % Td) << 2);       // pull v[(lane+16)%48]
    const int a32 = (((lane + 32) % Td) << 2);       // pull v[(lane+32)%48]

    // ---- E (fwd) / E^T (bwd) in gather-permuted SCALAR order, 48 regs ----
    float eA0[16], eA1[16], eA2[16];
#pragma unroll
    for (int h = 0; h < 3; ++h) {
        float* dst = (h == 0) ? eA0 : (h == 1) ? eA1 : eA2;
        const int blk = 16 * ((r0 + h) % 3);
#pragma unroll
        for (int i = 0; i < 16; ++i) {
            const int cc = blk + ((p + d * i) & 15);
            float e0 = 0.f;
            if (!isb) {
                if (lane < NTAG) e0 = __expf(tl[lane * Td + cc]);  // sink rows 0
            } else {
                if (lane < Td)   e0 = __expf(tl[cc * Td + lane]);
            }
            dst[i] = e0;
        }
    }

    // ---- chain init ----
    const int lidx = (lane < Td) ? lane : 0;
    const float* frow = feats + bS * Td;
    const int Fh = (len + 1) >> 1;
    const int act = rfl_i(isb ? (len - Fh) : (Fh - 1));
    const int it0 = isb ? (len - 1) : 0;

    float einit;
    if (!isb) einit = (lane < NTAG) ? __expf(tl[lane * Td + START_]) : 0.f;
    else      einit = (lane < Td)   ? __expf(tl[STOP_ * Td + lane])  : 0.f;

    float v  = __expf(frow[(size_t)it0 * Td + lidx]) * einit;
    float uf = einit;                 // bwd act==0 case: wstop
    int L = 0, kx; float sc;
    { int kb = rfl_i(__float_as_int(v)); kx = ((kb >> 23) & 0xFF) - 127;
      sc = __int_as_float((127 - kx) << 23); }

    // ---- emission prefetch: 8 slots, PRE-EXP'd; uniform ptr + scalar advance ----
    auto eidx0 = [&](int s) -> int {
        if (!isb) { int t = 1 + s; return t < Sd ? t : (Sd - 1); }
        int t = len - 2 - s; return t > 0 ? t : 0;
    };
    float pf0 = __expf(frow[(size_t)eidx0(0) * Td + lidx]);
    float pf1 = __expf(frow[(size_t)eidx0(1) * Td + lidx]);
    float pf2 = __expf(frow[(size_t)eidx0(2) * Td + lidx]);
    float pf3 = __expf(frow[(size_t)eidx0(3) * Td + lidx]);
    float pf4 = __expf(frow[(size_t)eidx0(4) * Td + lidx]);
    float pf5 = __expf(frow[(size_t)eidx0(5) * Td + lidx]);
    float pf6 = __expf(frow[(size_t)eidx0(6) * Td + lidx]);
    float pf7 = __expf(frow[(size_t)eidx0(7) * Td + lidx]);
    int tn = eidx0(8);
    const float* pcur = frow + (size_t)tn * Td;
    const int sAdv = isb ? -Td : Td;
    const int sInc = isb ? -1 : 1;
    const int tmax = Sd - 1;

    int s = 0;
    while (s + 8 <= act) {
        STEP1(pf0); pf0 = __expf(pcur[lidx]); ADVP();
        STEP1(pf1); pf1 = __expf(pcur[lidx]); ADVP();
        STEP1(pf2); pf2 = __expf(pcur[lidx]); ADVP();
        STEP1(pf3); pf3 = __expf(pcur[lidx]); ADVP();
        STEP1(pf4); pf4 = __expf(pcur[lidx]); ADVP();
        STEP1(pf5); pf5 = __expf(pcur[lidx]); ADVP();
        STEP1(pf6); pf6 = __expf(pcur[lidx]); ADVP();
        STEP1(pf7); pf7 = __expf(pcur[lidx]); ADVP();
        s += 8;
    }
    if (s < act) { STEP1(pf0); ++s; }
    if (s < act) { STEP1(pf1); ++s; }
    if (s < act) { STEP1(pf2); ++s; }
    if (s < act) { STEP1(pf3); ++s; }
    if (s < act) { STEP1(pf4); ++s; }
    if (s < act) { STEP1(pf5); ++s; }
    if (s < act) { STEP1(pf6); ++s; }

    // ---- publish meeting pieces (component-major for coalesced combine) ----
    if (!isb) {
        if (lane < Td) wsv[lane * Bn + b] = v;
        if (lane == 0) wsLF[b] = L;
    } else {
        if (lane < Td) wsu[lane * Bn + b] = uf;
        if (lane == 0) wsLB[b] = L;
    }
}

__launch_bounds__(64)
__global__ void crf_combine(const float* __restrict__ wsv,
                            const float* __restrict__ wsu,
                            const int* __restrict__ wsLF,
                            const int* __restrict__ wsLB,
                            const float* __restrict__ wsg,
                            float* __restrict__ out, int Bn)
{
    const int b = blockIdx.x * 64 + threadIdx.x;
    if (b >= Bn) return;
    float dot = 0.f;
#pragma unroll
    for (int j = 0; j < Td; ++j)
        dot += wsv[j * Bn + b] * wsu[j * Bn + b];
    const float ln2 = 0.6931471805599453f;
    out[b] = (float)(wsLF[b] + wsLB[b]) * ln2 + __logf(dot) - wsg[b];
}

extern "C" void kernel_launch(void* const* d_in, const int* in_sizes, int n_in,
                              void* d_out, int out_size, void* d_ws, size_t ws_size,
                              hipStream_t stream) {
    const float* feats = (const float*)d_in[0];
    const float* masks = (const float*)d_in[1];
    const int*   tags  = (const int*)d_in[2];
    const float* trans = (const float*)d_in[3];
    float* outp = (float*)d_out;

    const int Bn = in_sizes[1] / Sd;                 // B = 512

    float* wsv  = (float*)d_ws;                      // [48][Bn]
    float* wsu  = wsv + (size_t)Td * Bn;             // [48][Bn]
    int*   wsLF = (int*)(wsu + (size_t)Td * Bn);     // [Bn]
    int*   wsLB = wsLF + Bn;                         // [Bn]
    float* wsg  = (float*)(wsLB + Bn);               // [Bn]

    crf_chains<<<dim3(2 * Bn), dim3(64), 0, stream>>>(feats, masks, tags, trans,
                                                      wsv, wsu, wsLF, wsLB, wsg, Bn);
    crf_combine<<<dim3((Bn + 63) / 64), dim3(64), 0, stream>>>(wsv, wsu, wsLF, wsLB, wsg, outp, Bn);
}